// Round 5
// baseline (1047.591 us; speedup 1.0000x reference)
//
#include <hip/hip_runtime.h>

#define NN 100000
#define NE 1600000
#define NG 512
#define HID 128
#define FPD 2048
#define BSHIFT 8
#define NBUK ((NN + 255) >> 8)   // 391
#define BCAP 5120

typedef __attribute__((ext_vector_type(8))) short bf16x8;
typedef __attribute__((ext_vector_type(4))) float f32x4;

static __device__ __forceinline__ ushort f2bf(float f) {
  union { float f; uint u; } v; v.f = f;
  uint u = v.u;
  uint r = (u + 0x7fffu + ((u >> 16) & 1u)) >> 16;  // RNE
  return (ushort)r;
}
static __device__ __forceinline__ float bf2f(ushort h) {
  union { uint u; float f; } v; v.u = ((uint)h) << 16;
  return v.f;
}

// ---------------- bucketed CSR build ----------------

__global__ __launch_bounds__(256) void bucket_scatter(const int* __restrict__ src,
                                                      const int* __restrict__ dst,
                                                      int* __restrict__ bcnt,
                                                      uint2* __restrict__ bbuf, int E) {
  int i = blockIdx.x * 256 + threadIdx.x;
  if (i < E) {
    int d = dst[i];
    int b = d >> BSHIFT;
    int p = atomicAdd(&bcnt[b], 1);
    bbuf[(size_t)b * BCAP + p] = make_uint2((uint)d, (uint)src[i]);
  }
}

__global__ __launch_bounds__(256) void bucket_hist(const int* __restrict__ bcnt,
                                                   const uint2* __restrict__ bbuf,
                                                   int* __restrict__ cnt) {
  __shared__ int h[256];
  int b = blockIdx.x, t = threadIdx.x;
  h[t] = 0;
  __syncthreads();
  int n = bcnt[b];
  const uint2* bb = bbuf + (size_t)b * BCAP;
  for (int e = t; e < n; e += 256) atomicAdd(&h[bb[e].x & 255], 1);
  __syncthreads();
  int node = (b << BSHIFT) + t;
  if (node < NN) cnt[node] = h[t];
}

__global__ __launch_bounds__(256) void scan1_kernel(const int* __restrict__ cnt,
                                                    int* __restrict__ partial,
                                                    int* __restrict__ bsums, int n) {
  __shared__ int lds[256];
  int t = threadIdx.x;
  int base = blockIdx.x * 1024 + t * 4;
  int4 v = make_int4(0, 0, 0, 0);
  if (base + 3 < n) {
    v = *reinterpret_cast<const int4*>(&cnt[base]);
  } else {
    if (base     < n) v.x = cnt[base];
    if (base + 1 < n) v.y = cnt[base + 1];
    if (base + 2 < n) v.z = cnt[base + 2];
    if (base + 3 < n) v.w = cnt[base + 3];
  }
  int s = v.x + v.y + v.z + v.w;
  lds[t] = s;
  __syncthreads();
  for (int off = 1; off < 256; off <<= 1) {
    int add = (t >= off) ? lds[t - off] : 0;
    __syncthreads();
    lds[t] += add;
    __syncthreads();
  }
  int run = lds[t] - s;
  run += v.x; if (base     < n) partial[base]     = run;
  run += v.y; if (base + 1 < n) partial[base + 1] = run;
  run += v.z; if (base + 2 < n) partial[base + 2] = run;
  run += v.w; if (base + 3 < n) partial[base + 3] = run;
  if (t == 255) bsums[blockIdx.x] = lds[255];
}

__global__ __launch_bounds__(256) void scan2_kernel(int* __restrict__ bsums, int nb) {
  __shared__ int lds[256];
  int t = threadIdx.x;
  int s = (t < nb) ? bsums[t] : 0;
  lds[t] = s;
  __syncthreads();
  for (int off = 1; off < 256; off <<= 1) {
    int add = (t >= off) ? lds[t - off] : 0;
    __syncthreads();
    lds[t] += add;
    __syncthreads();
  }
  if (t < nb) bsums[t] = lds[t] - s;
}

__global__ __launch_bounds__(256) void scan3_kernel(const int* __restrict__ partial,
                                                    const int* __restrict__ bsums,
                                                    int* __restrict__ rowptr, int n) {
  int i = blockIdx.x * 256 + threadIdx.x;
  if (i == 0) rowptr[0] = 0;
  if (i < n) rowptr[i + 1] = partial[i] + bsums[i >> 10];
}

__global__ __launch_bounds__(256) void bucket_place(const int* __restrict__ bcnt,
                                                    const uint2* __restrict__ bbuf,
                                                    const int* __restrict__ rowptr,
                                                    int* __restrict__ cols) {
  __shared__ int cur[256];
  int b = blockIdx.x, t = threadIdx.x;
  int node = (b << BSHIFT) + t;
  cur[t] = rowptr[node < NN ? node : NN];
  __syncthreads();
  int n = bcnt[b];
  const uint2* bb = bbuf + (size_t)b * BCAP;
  for (int e = t; e < n; e += 256) {
    uint2 p = bb[e];
    int pos = atomicAdd(&cur[p.x & 255], 1);
    cols[pos] = (int)p.y;
  }
}

// ---------------- conversions ----------------

__global__ __launch_bounds__(256) void cvt_x_split(const float* __restrict__ x,
                                                   ushort* __restrict__ xh,
                                                   ushort* __restrict__ xl, int n4) {
  int i = blockIdx.x * 256 + threadIdx.x;
  if (i < n4) {
    float4 v = *reinterpret_cast<const float4*>(&x[i * 4]);
    ushort4 h, l;
    h.x = f2bf(v.x); l.x = f2bf(v.x - bf2f(h.x));
    h.y = f2bf(v.y); l.y = f2bf(v.y - bf2f(h.y));
    h.z = f2bf(v.z); l.z = f2bf(v.z - bf2f(h.z));
    h.w = f2bf(v.w); l.w = f2bf(v.w - bf2f(h.w));
    *reinterpret_cast<ushort4*>(&xh[i * 4]) = h;
    *reinterpret_cast<ushort4*>(&xl[i * 4]) = l;
  }
}

// transpose + hi/lo split 5 [128][128] weights: Wt[w][j][k] = W[k][j]
__global__ __launch_bounds__(256) void cvt_w10(const float* __restrict__ w0,
                                               const float* __restrict__ w1,
                                               const float* __restrict__ w2,
                                               const float* __restrict__ w3,
                                               const float* __restrict__ w4,
                                               ushort* __restrict__ outh,
                                               ushort* __restrict__ outl) {
  int idx = blockIdx.x * 256 + threadIdx.x;  // 5*16384
  if (idx >= 5 * 16384) return;
  int w = idx >> 14, rem = idx & 16383;
  int j = rem >> 7, k = rem & 127;
  const float* W = (w == 0) ? w0 : (w == 1) ? w1 : (w == 2) ? w2 : (w == 3) ? w3 : w4;
  float v = W[k * 128 + j];
  ushort h = f2bf(v);
  outh[idx] = h;
  outl[idx] = f2bf(v - bf2f(h));
}

// ---------------- aggregation (bf16 in, hi/lo bf16 out) ----------------

__global__ __launch_bounds__(256) void agg_bf16(const ushort* __restrict__ H,
                                                const int* __restrict__ rowptr,
                                                const int* __restrict__ cols,
                                                ushort* __restrict__ outh,
                                                ushort* __restrict__ outl) {
  int node = blockIdx.x * 4 + (threadIdx.x >> 6);
  int lane = threadIdx.x & 63;
  int s = rowptr[node], e = rowptr[node + 1];
  float a0 = 0.f, a1 = 0.f;
  int i = s;
  for (; i + 3 < e; i += 4) {
    int c0 = cols[i], c1 = cols[i + 1], c2 = cols[i + 2], c3 = cols[i + 3];
    uint u0 = *reinterpret_cast<const uint*>(&H[(size_t)c0 * 128 + lane * 2]);
    uint u1 = *reinterpret_cast<const uint*>(&H[(size_t)c1 * 128 + lane * 2]);
    uint u2 = *reinterpret_cast<const uint*>(&H[(size_t)c2 * 128 + lane * 2]);
    uint u3 = *reinterpret_cast<const uint*>(&H[(size_t)c3 * 128 + lane * 2]);
    a0 += bf2f((ushort)(u0 & 0xffff)) + bf2f((ushort)(u1 & 0xffff)) +
          bf2f((ushort)(u2 & 0xffff)) + bf2f((ushort)(u3 & 0xffff));
    a1 += bf2f((ushort)(u0 >> 16)) + bf2f((ushort)(u1 >> 16)) +
          bf2f((ushort)(u2 >> 16)) + bf2f((ushort)(u3 >> 16));
  }
  for (; i < e; ++i) {
    uint u0 = *reinterpret_cast<const uint*>(&H[(size_t)cols[i] * 128 + lane * 2]);
    a0 += bf2f((ushort)(u0 & 0xffff));
    a1 += bf2f((ushort)(u0 >> 16));
  }
  ushort h0 = f2bf(a0), h1 = f2bf(a1);
  ushort l0 = f2bf(a0 - bf2f(h0)), l1 = f2bf(a1 - bf2f(h1));
  *reinterpret_cast<uint*>(&outh[(size_t)node * 128 + lane * 2]) = (uint)h0 | ((uint)h1 << 16);
  *reinterpret_cast<uint*>(&outl[(size_t)node * 128 + lane * 2]) = (uint)l0 | ((uint)l1 << 16);
}

// ---------------- W-stationary MFMA GEMM ----------------
// MODE 0: C = prelu(A1@W1 + bias)          terms: A1h@W1h + A1h@W1l + A1l@W1h
// MODE 1: C = prelu(A1@W1 + A2@W2 + bias)  terms: + A2@W2h + A2@W2l   (bf16 out)
// MODE 2: same as 1, fp32 out
// 256 thr = 4 waves; block = 128 rows; wave w owns cols [32w,32w+32) (n-tiles 2w,2w+1).
// W fragments preloaded to registers ONCE per wave; A streams per 16-row group.

template <int MODE>
__global__ __launch_bounds__(256, 2) void gemm_mfma(const ushort* __restrict__ A1h,
                                                    const ushort* __restrict__ A1l,
                                                    const ushort* __restrict__ A2,
                                                    const ushort* __restrict__ W1h,
                                                    const ushort* __restrict__ W1l,
                                                    const ushort* __restrict__ W2h,
                                                    const ushort* __restrict__ W2l,
                                                    const float* __restrict__ bias,
                                                    const float* __restrict__ pa,
                                                    ushort* __restrict__ Cb,
                                                    float* __restrict__ Cf, int rows) {
  int t = threadIdx.x;
  int wave = t >> 6, lane = t & 63;
  int lrow = lane & 15, lk = lane >> 4;
  int r0 = blockIdx.x * 128;
  int n0 = wave << 1;

  const bf16x8* Wv1h = reinterpret_cast<const bf16x8*>(W1h);
  const bf16x8* Wv1l = reinterpret_cast<const bf16x8*>(W1l);
  const bf16x8* Wv2h = reinterpret_cast<const bf16x8*>(W2h);
  const bf16x8* Wv2l = reinterpret_cast<const bf16x8*>(W2l);

  // W-stationary register fragments
  bf16x8 w1h[2][4], w1l[2][4], w2h[2][4], w2l[2][4];
#pragma unroll
  for (int ni = 0; ni < 2; ++ni)
#pragma unroll
    for (int ks = 0; ks < 4; ++ks) {
      int wi = ((((n0 + ni) << 4) + lrow) << 4) + (ks << 2) + lk;
      w1h[ni][ks] = Wv1h[wi];
      w1l[ni][ks] = Wv1l[wi];
      if (MODE >= 1) {
        w2h[ni][ks] = Wv2h[wi];
        w2l[ni][ks] = Wv2l[wi];
      }
    }

  float bv[2], av[2];
#pragma unroll
  for (int ni = 0; ni < 2; ++ni) {
    int col = ((n0 + ni) << 4) + lrow;
    bv[ni] = bias ? bias[col] : 0.f;
    av[ni] = pa ? pa[col] : 1.f;
  }

#pragma unroll 2
  for (int rg = 0; rg < 8; ++rg) {
    int r = r0 + (rg << 4) + lrow;
    if (r > rows - 1) r = rows - 1;
    size_t off = (size_t)r * 128 + (lk << 3);
    bf16x8 a1h[4], a1l[4], a2f[4];
#pragma unroll
    for (int ks = 0; ks < 4; ++ks) {
      a1h[ks] = *reinterpret_cast<const bf16x8*>(A1h + off + (ks << 5));
      a1l[ks] = *reinterpret_cast<const bf16x8*>(A1l + off + (ks << 5));
      if (MODE >= 1) a2f[ks] = *reinterpret_cast<const bf16x8*>(A2 + off + (ks << 5));
    }
    f32x4 acc[2] = {(f32x4){0.f, 0.f, 0.f, 0.f}, (f32x4){0.f, 0.f, 0.f, 0.f}};
#pragma unroll
    for (int ks = 0; ks < 4; ++ks) {
#pragma unroll
      for (int ni = 0; ni < 2; ++ni) {
        acc[ni] = __builtin_amdgcn_mfma_f32_16x16x32_bf16(a1h[ks], w1h[ni][ks], acc[ni], 0, 0, 0);
        acc[ni] = __builtin_amdgcn_mfma_f32_16x16x32_bf16(a1h[ks], w1l[ni][ks], acc[ni], 0, 0, 0);
        acc[ni] = __builtin_amdgcn_mfma_f32_16x16x32_bf16(a1l[ks], w1h[ni][ks], acc[ni], 0, 0, 0);
        if (MODE >= 1) {
          acc[ni] = __builtin_amdgcn_mfma_f32_16x16x32_bf16(a2f[ks], w2h[ni][ks], acc[ni], 0, 0, 0);
          acc[ni] = __builtin_amdgcn_mfma_f32_16x16x32_bf16(a2f[ks], w2l[ni][ks], acc[ni], 0, 0, 0);
        }
      }
    }
    // epilogue: C/D layout col=lane&15, row_in_tile=(lane>>4)*4+j
#pragma unroll
    for (int ni = 0; ni < 2; ++ni) {
      int col = ((n0 + ni) << 4) + lrow;
#pragma unroll
      for (int j = 0; j < 4; ++j) {
        int rr = r0 + (rg << 4) + (lk << 2) + j;
        if (rr < rows) {
          float xv = acc[ni][j] + bv[ni];
          if (pa) xv = xv > 0.f ? xv : av[ni] * xv;
          if (MODE == 2) Cf[(size_t)rr * 128 + col] = xv;
          else           Cb[(size_t)rr * 128 + col] = f2bf(xv);
        }
      }
    }
  }
}

// ---------------- mean pool over sorted batch (fp32) ----------------

__device__ __forceinline__ int lower_bound_dev(const int* __restrict__ arr, int n, int val) {
  int lo = 0, hi = n;
  while (lo < hi) {
    int mid = (lo + hi) >> 1;
    if (arr[mid] < val) lo = mid + 1; else hi = mid;
  }
  return lo;
}

__global__ __launch_bounds__(128) void pool_mean(const float* __restrict__ H,
                                                 const int* __restrict__ batch,
                                                 float* __restrict__ pooled) {
  int g = blockIdx.x;
  int t = threadIdx.x;
  int start = lower_bound_dev(batch, NN, g);
  int end = lower_bound_dev(batch, NN, g + 1);
  float acc = 0.f;
  for (int r = start; r < end; ++r) acc += H[(size_t)r * 128 + t];
  int c = end - start;
  float inv = 1.f / (float)(c > 0 ? c : 1);
  pooled[g * 128 + t] = acc * inv;
}

// ---------------- fingerprint head (fp32) ----------------

__global__ __launch_bounds__(128) void fp_head(const float* __restrict__ fp,
                                               const float* __restrict__ Wfp,
                                               const float* __restrict__ bfp,
                                               const float* __restrict__ afp,
                                               float* __restrict__ femb) {
  __shared__ __align__(16) float fs[FPD];
  int g = blockIdx.x;
  int j = threadIdx.x;
  for (int i = j; i < FPD; i += 128) fs[i] = fp[g * FPD + i];
  __syncthreads();
  float acc = bfp[j];
  for (int k = 0; k < FPD; ++k) acc += fs[k] * Wfp[k * 128 + j];
  float a = afp[j];
  femb[g * 128 + j] = acc > 0.f ? acc : a * acc;
}

// ---------------- final ----------------

__global__ __launch_bounds__(64) void final_out(const float* __restrict__ pooled,
                                                const float* __restrict__ femb,
                                                const float* __restrict__ Wp,
                                                const float* __restrict__ bp,
                                                float* __restrict__ out) {
  int g = blockIdx.x;
  int t = threadIdx.x;
  float acc = 0.f;
  for (int i = t; i < 128; i += 64)
    acc += pooled[g * 128 + i] * Wp[i] + femb[g * 128 + i] * Wp[128 + i];
  for (int off = 32; off > 0; off >>= 1) acc += __shfl_down(acc, off);
  if (t == 0) out[g] = acc + bp[0];
}

// ---------------- launch ----------------

extern "C" void kernel_launch(void* const* d_in, const int* in_sizes, int n_in,
                              void* d_out, int out_size, void* d_ws, size_t ws_size,
                              hipStream_t stream) {
  const float* x      = (const float*)d_in[0];
  const float* fp     = (const float*)d_in[1];
  const int*   ei     = (const int*)d_in[2];
  const int*   batch  = (const int*)d_in[3];
  const float* W_pre  = (const float*)d_in[4];
  const float* b_pre  = (const float*)d_in[5];
  const float* a_pre  = (const float*)d_in[6];
  const float* Wl1    = (const float*)d_in[7];
  const float* bl1    = (const float*)d_in[8];
  const float* Wr1    = (const float*)d_in[9];
  const float* a1     = (const float*)d_in[10];
  const float* Wl2    = (const float*)d_in[11];
  const float* bl2    = (const float*)d_in[12];
  const float* Wr2    = (const float*)d_in[13];
  const float* a2     = (const float*)d_in[14];
  const float* W_fp   = (const float*)d_in[15];
  const float* b_fp   = (const float*)d_in[16];
  const float* a_fp   = (const float*)d_in[17];
  const float* W_post = (const float*)d_in[18];
  const float* b_post = (const float*)d_in[19];

  const int* src = ei;
  const int* dst = ei + NE;

  const size_t NBUF = (size_t)NN * 128;
  ushort* buf0 = (ushort*)d_ws;          // x_hi -> agg_hi
  ushort* buf1 = buf0 + NBUF;            // x_lo -> agg_lo
  ushort* buf2 = buf1 + NBUF;            // h0
  ushort* buf3 = buf2 + NBUF;            // h1
  float*  h2f  = (float*)(buf3 + NBUF);  // h2 fp32
  ushort* Wth  = (ushort*)(h2f + NBUF);  // 5*16384
  ushort* Wtl  = Wth + 5 * 16384;        // 5*16384
  int* cnt     = (int*)(Wtl + 5 * 16384);
  int* rowptr  = cnt + NN;               // NN+1 (pad)
  int* bsums   = rowptr + NN + 4;        // 128
  int* partial = bsums + 128;            // NN
  int* colsA   = partial + NN;           // NE
  int* bcnt    = colsA + NE;             // NBUK (pad to 4)
  uint2* bbuf  = (uint2*)(bcnt + ((NBUK + 3) & ~3));  // NBUK*BCAP*8B = 16MB
  float* pooled = (float*)(bbuf + (size_t)NBUK * BCAP);
  float* femb   = pooled + NG * 128;

  // --- bucketed CSR build (dst -> srcs) ---
  hipMemsetAsync(bcnt, 0, NBUK * sizeof(int), stream);
  bucket_scatter<<<(NE + 255) / 256, 256, 0, stream>>>(src, dst, bcnt, bbuf, NE);
  bucket_hist<<<NBUK, 256, 0, stream>>>(bcnt, bbuf, cnt);
  int nb = (NN + 1023) / 1024;  // 98
  scan1_kernel<<<nb, 256, 0, stream>>>(cnt, partial, bsums, NN);
  scan2_kernel<<<1, 256, 0, stream>>>(bsums, nb);
  scan3_kernel<<<(NN + 255) / 256, 256, 0, stream>>>(partial, bsums, rowptr, NN);
  bucket_place<<<NBUK, 256, 0, stream>>>(bcnt, bbuf, rowptr, colsA);

  // --- conversions ---
  cvt_x_split<<<(NN * 128 / 4 + 255) / 256, 256, 0, stream>>>(x, buf0, buf1, NN * 128 / 4);
  cvt_w10<<<(5 * 16384 + 255) / 256, 256, 0, stream>>>(W_pre, Wl1, Wr1, Wl2, Wr2, Wth, Wtl);

  const ushort* Wh_pre = Wth;
  const ushort* Wh_l1  = Wth + 16384;
  const ushort* Wh_r1  = Wth + 32768;
  const ushort* Wh_l2  = Wth + 49152;
  const ushort* Wh_r2  = Wth + 65536;
  const ushort* Wl_pre = Wtl;
  const ushort* Wl_l1  = Wtl + 16384;
  const ushort* Wl_r1  = Wtl + 32768;
  const ushort* Wl_l2  = Wtl + 49152;
  const ushort* Wl_r2  = Wtl + 65536;

  int gGemm = (NN + 127) / 128;  // 782

  // pre_mp: h0 = prelu(x@W_pre + b_pre) -> buf2
  gemm_mfma<0><<<gGemm, 256, 0, stream>>>(buf0, buf1, nullptr, Wh_pre, Wl_pre, nullptr,
                                          nullptr, b_pre, a_pre, buf2, nullptr, NN);

  // conv1: agg(h0) -> buf0/buf1; h1 = prelu(agg@Wl1 + h0@Wr1 + bl1) -> buf3
  agg_bf16<<<NN / 4, 256, 0, stream>>>(buf2, rowptr, colsA, buf0, buf1);
  gemm_mfma<1><<<gGemm, 256, 0, stream>>>(buf0, buf1, buf2, Wh_l1, Wl_l1, Wh_r1, Wl_r1,
                                          bl1, a1, buf3, nullptr, NN);

  // conv2: agg(h1) -> buf0/buf1; h2 = prelu(agg@Wl2 + h1@Wr2 + bl2) -> h2f (fp32)
  agg_bf16<<<NN / 4, 256, 0, stream>>>(buf3, rowptr, colsA, buf0, buf1);
  gemm_mfma<2><<<gGemm, 256, 0, stream>>>(buf0, buf1, buf3, Wh_l2, Wl_l2, Wh_r2, Wl_r2,
                                          bl2, a2, nullptr, h2f, NN);

  // pool + heads
  pool_mean<<<NG, 128, 0, stream>>>(h2f, batch, pooled);
  fp_head<<<NG, 128, 0, stream>>>(fp, W_fp, b_fp, a_fp, femb);
  final_out<<<NG, 64, 0, stream>>>(pooled, femb, W_post, b_post, (float*)d_out);
}

// Round 6
// 519.597 us; speedup vs baseline: 2.0162x; 2.0162x over previous
//
#include <hip/hip_runtime.h>

#define NN 100000
#define NE 1600000
#define NG 512
#define HID 128
#define FPD 2048
#define BSHIFT 8
#define NBUK ((NN + 255) >> 8)   // 391
#define BCAP 5120
#define EPB 4096
#define EPT 16

typedef __attribute__((ext_vector_type(8))) short bf16x8;
typedef __attribute__((ext_vector_type(4))) float f32x4;

static __device__ __forceinline__ ushort f2bf(float f) {
  union { float f; uint u; } v; v.f = f;
  uint u = v.u;
  uint r = (u + 0x7fffu + ((u >> 16) & 1u)) >> 16;  // RNE
  return (ushort)r;
}
static __device__ __forceinline__ float bf2f(ushort h) {
  union { uint u; float f; } v; v.u = ((uint)h) << 16;
  return v.f;
}

// ---------------- bucketed CSR build ----------------

// block-staged scatter: LDS histogram -> scan -> 1 atomic per (block,bucket) ->
// LDS-grouped staging -> coalesced run writes.
__global__ __launch_bounds__(256) void bucket_scatter(const int* __restrict__ src,
                                                      const int* __restrict__ dst,
                                                      int* __restrict__ bcnt,
                                                      uint2* __restrict__ bbuf, int E) {
  __shared__ int hist[NBUK];
  __shared__ int gbase[NBUK];
  __shared__ int lbase[NBUK + 1];
  __shared__ int sc[2][512];
  __shared__ uint2 stage[EPB];
  int t = threadIdx.x;
  int e0 = blockIdx.x * EPB;
  for (int i = t; i < NBUK; i += 256) hist[i] = 0;
  __syncthreads();

  int myb[EPT], myoff[EPT];
  uint2 myp[EPT];
#pragma unroll
  for (int u = 0; u < EPT; ++u) {
    int e = e0 + u * 256 + t;
    myb[u] = -1;
    if (e < E) {
      int d = dst[e];
      int b = d >> BSHIFT;
      myp[u] = make_uint2((uint)d, (uint)src[e]);
      myb[u] = b;
      myoff[u] = atomicAdd(&hist[b], 1);
    }
  }
  __syncthreads();

  // inclusive scan of hist[0..NBUK) over padded 512 (Hillis-Steele, dbuf)
  sc[0][t] = (t < NBUK) ? hist[t] : 0;
  sc[0][t + 256] = (t + 256 < NBUK) ? hist[t + 256] : 0;
  int pp = 0;
  for (int off = 1; off < 512; off <<= 1) {
    __syncthreads();
    int a0 = sc[pp][t] + ((t >= off) ? sc[pp][t - off] : 0);
    int a1 = sc[pp][t + 256] + ((t + 256 >= off) ? sc[pp][t + 256 - off] : 0);
    sc[1 - pp][t] = a0;
    sc[1 - pp][t + 256] = a1;
    pp = 1 - pp;
  }
  __syncthreads();
  if (t < NBUK) lbase[t] = (t == 0) ? 0 : sc[pp][t - 1];
  if (t + 256 < NBUK) lbase[t + 256] = sc[pp][t + 255];
  if (t == 0) lbase[NBUK] = sc[pp][NBUK - 1];
  // reserve global ranges: one atomic per non-empty bucket
  for (int i = t; i < NBUK; i += 256)
    if (hist[i] > 0) gbase[i] = atomicAdd(&bcnt[i], hist[i]);
  __syncthreads();

  // stage pairs grouped by bucket
#pragma unroll
  for (int u = 0; u < EPT; ++u)
    if (myb[u] >= 0) stage[lbase[myb[u]] + myoff[u]] = myp[u];
  __syncthreads();

  int total = lbase[NBUK];
  for (int j = t; j < total; j += 256) {
    int lo = 0, hi = NBUK - 1;   // largest b with lbase[b] <= j
    while (lo < hi) {
      int mid = (lo + hi + 1) >> 1;
      if (lbase[mid] <= j) lo = mid; else hi = mid - 1;
    }
    bbuf[(size_t)lo * BCAP + gbase[lo] + (j - lbase[lo])] = stage[j];
  }
}

__global__ __launch_bounds__(256) void bucket_hist(const int* __restrict__ bcnt,
                                                   const uint2* __restrict__ bbuf,
                                                   int* __restrict__ cnt) {
  __shared__ int h[256];
  int b = blockIdx.x, t = threadIdx.x;
  h[t] = 0;
  __syncthreads();
  int n = bcnt[b];
  const uint2* bb = bbuf + (size_t)b * BCAP;
  for (int e = t; e < n; e += 256) atomicAdd(&h[bb[e].x & 255], 1);
  __syncthreads();
  int node = (b << BSHIFT) + t;
  if (node < NN) cnt[node] = h[t];
}

__global__ __launch_bounds__(256) void scan1_kernel(const int* __restrict__ cnt,
                                                    int* __restrict__ partial,
                                                    int* __restrict__ bsums, int n) {
  __shared__ int lds[256];
  int t = threadIdx.x;
  int base = blockIdx.x * 1024 + t * 4;
  int4 v = make_int4(0, 0, 0, 0);
  if (base + 3 < n) {
    v = *reinterpret_cast<const int4*>(&cnt[base]);
  } else {
    if (base     < n) v.x = cnt[base];
    if (base + 1 < n) v.y = cnt[base + 1];
    if (base + 2 < n) v.z = cnt[base + 2];
    if (base + 3 < n) v.w = cnt[base + 3];
  }
  int s = v.x + v.y + v.z + v.w;
  lds[t] = s;
  __syncthreads();
  for (int off = 1; off < 256; off <<= 1) {
    int add = (t >= off) ? lds[t - off] : 0;
    __syncthreads();
    lds[t] += add;
    __syncthreads();
  }
  int run = lds[t] - s;
  run += v.x; if (base     < n) partial[base]     = run;
  run += v.y; if (base + 1 < n) partial[base + 1] = run;
  run += v.z; if (base + 2 < n) partial[base + 2] = run;
  run += v.w; if (base + 3 < n) partial[base + 3] = run;
  if (t == 255) bsums[blockIdx.x] = lds[255];
}

__global__ __launch_bounds__(256) void scan2_kernel(int* __restrict__ bsums, int nb) {
  __shared__ int lds[256];
  int t = threadIdx.x;
  int s = (t < nb) ? bsums[t] : 0;
  lds[t] = s;
  __syncthreads();
  for (int off = 1; off < 256; off <<= 1) {
    int add = (t >= off) ? lds[t - off] : 0;
    __syncthreads();
    lds[t] += add;
    __syncthreads();
  }
  if (t < nb) bsums[t] = lds[t] - s;
}

__global__ __launch_bounds__(256) void scan3_kernel(const int* __restrict__ partial,
                                                    const int* __restrict__ bsums,
                                                    int* __restrict__ rowptr, int n) {
  int i = blockIdx.x * 256 + threadIdx.x;
  if (i == 0) rowptr[0] = 0;
  if (i < n) rowptr[i + 1] = partial[i] + bsums[i >> 10];
}

__global__ __launch_bounds__(256) void bucket_place(const int* __restrict__ bcnt,
                                                    const uint2* __restrict__ bbuf,
                                                    const int* __restrict__ rowptr,
                                                    int* __restrict__ cols) {
  __shared__ int cur[256];
  int b = blockIdx.x, t = threadIdx.x;
  int node = (b << BSHIFT) + t;
  cur[t] = rowptr[node < NN ? node : NN];
  __syncthreads();
  int n = bcnt[b];
  const uint2* bb = bbuf + (size_t)b * BCAP;
  for (int e = t; e < n; e += 256) {
    uint2 p = bb[e];
    int pos = atomicAdd(&cur[p.x & 255], 1);
    cols[pos] = (int)p.y;
  }
}

// ---------------- conversions ----------------

__global__ __launch_bounds__(256) void cvt_x_split(const float* __restrict__ x,
                                                   ushort* __restrict__ xh,
                                                   ushort* __restrict__ xl, int n4) {
  int i = blockIdx.x * 256 + threadIdx.x;
  if (i < n4) {
    float4 v = *reinterpret_cast<const float4*>(&x[i * 4]);
    ushort4 h, l;
    h.x = f2bf(v.x); l.x = f2bf(v.x - bf2f(h.x));
    h.y = f2bf(v.y); l.y = f2bf(v.y - bf2f(h.y));
    h.z = f2bf(v.z); l.z = f2bf(v.z - bf2f(h.z));
    h.w = f2bf(v.w); l.w = f2bf(v.w - bf2f(h.w));
    *reinterpret_cast<ushort4*>(&xh[i * 4]) = h;
    *reinterpret_cast<ushort4*>(&xl[i * 4]) = l;
  }
}

// transpose + hi/lo split 5 [128][128] weights: Wt[w][j][k] = W[k][j]
__global__ __launch_bounds__(256) void cvt_w10(const float* __restrict__ w0,
                                               const float* __restrict__ w1,
                                               const float* __restrict__ w2,
                                               const float* __restrict__ w3,
                                               const float* __restrict__ w4,
                                               ushort* __restrict__ outh,
                                               ushort* __restrict__ outl) {
  int idx = blockIdx.x * 256 + threadIdx.x;  // 5*16384
  if (idx >= 5 * 16384) return;
  int w = idx >> 14, rem = idx & 16383;
  int j = rem >> 7, k = rem & 127;
  const float* W = (w == 0) ? w0 : (w == 1) ? w1 : (w == 2) ? w2 : (w == 3) ? w3 : w4;
  float v = W[k * 128 + j];
  ushort h = f2bf(v);
  outh[idx] = h;
  outl[idx] = f2bf(v - bf2f(h));
}

// ---------------- aggregation (bf16 in, hi/lo bf16 out) ----------------

__global__ __launch_bounds__(256) void agg_bf16(const ushort* __restrict__ H,
                                                const int* __restrict__ rowptr,
                                                const int* __restrict__ cols,
                                                ushort* __restrict__ outh,
                                                ushort* __restrict__ outl) {
  int node = blockIdx.x * 4 + (threadIdx.x >> 6);
  int lane = threadIdx.x & 63;
  int s = rowptr[node], e = rowptr[node + 1];
  float a0 = 0.f, a1 = 0.f;
  int i = s;
  for (; i + 3 < e; i += 4) {
    int c0 = cols[i], c1 = cols[i + 1], c2 = cols[i + 2], c3 = cols[i + 3];
    uint u0 = *reinterpret_cast<const uint*>(&H[(size_t)c0 * 128 + lane * 2]);
    uint u1 = *reinterpret_cast<const uint*>(&H[(size_t)c1 * 128 + lane * 2]);
    uint u2 = *reinterpret_cast<const uint*>(&H[(size_t)c2 * 128 + lane * 2]);
    uint u3 = *reinterpret_cast<const uint*>(&H[(size_t)c3 * 128 + lane * 2]);
    a0 += bf2f((ushort)(u0 & 0xffff)) + bf2f((ushort)(u1 & 0xffff)) +
          bf2f((ushort)(u2 & 0xffff)) + bf2f((ushort)(u3 & 0xffff));
    a1 += bf2f((ushort)(u0 >> 16)) + bf2f((ushort)(u1 >> 16)) +
          bf2f((ushort)(u2 >> 16)) + bf2f((ushort)(u3 >> 16));
  }
  for (; i < e; ++i) {
    uint u0 = *reinterpret_cast<const uint*>(&H[(size_t)cols[i] * 128 + lane * 2]);
    a0 += bf2f((ushort)(u0 & 0xffff));
    a1 += bf2f((ushort)(u0 >> 16));
  }
  ushort h0 = f2bf(a0), h1 = f2bf(a1);
  ushort l0 = f2bf(a0 - bf2f(h0)), l1 = f2bf(a1 - bf2f(h1));
  *reinterpret_cast<uint*>(&outh[(size_t)node * 128 + lane * 2]) = (uint)h0 | ((uint)h1 << 16);
  *reinterpret_cast<uint*>(&outl[(size_t)node * 128 + lane * 2]) = (uint)l0 | ((uint)l1 << 16);
}

// ---------------- W-stationary MFMA GEMM ----------------
// MODE 0: C = prelu(A1@W1 + bias)          terms: A1h@W1h + A1h@W1l + A1l@W1h
// MODE 1: C = prelu(A1@W1 + A2@W2 + bias)  terms: + A2@W2h + A2@W2l   (bf16 out)
// MODE 2: same as 1, fp32 out

template <int MODE>
__global__ __launch_bounds__(256, 2) void gemm_mfma(const ushort* __restrict__ A1h,
                                                    const ushort* __restrict__ A1l,
                                                    const ushort* __restrict__ A2,
                                                    const ushort* __restrict__ W1h,
                                                    const ushort* __restrict__ W1l,
                                                    const ushort* __restrict__ W2h,
                                                    const ushort* __restrict__ W2l,
                                                    const float* __restrict__ bias,
                                                    const float* __restrict__ pa,
                                                    ushort* __restrict__ Cb,
                                                    float* __restrict__ Cf, int rows) {
  int t = threadIdx.x;
  int wave = t >> 6, lane = t & 63;
  int lrow = lane & 15, lk = lane >> 4;
  int r0 = blockIdx.x * 128;
  int n0 = wave << 1;

  const bf16x8* Wv1h = reinterpret_cast<const bf16x8*>(W1h);
  const bf16x8* Wv1l = reinterpret_cast<const bf16x8*>(W1l);
  const bf16x8* Wv2h = reinterpret_cast<const bf16x8*>(W2h);
  const bf16x8* Wv2l = reinterpret_cast<const bf16x8*>(W2l);

  bf16x8 w1h[2][4], w1l[2][4], w2h[2][4], w2l[2][4];
#pragma unroll
  for (int ni = 0; ni < 2; ++ni)
#pragma unroll
    for (int ks = 0; ks < 4; ++ks) {
      int wi = ((((n0 + ni) << 4) + lrow) << 4) + (ks << 2) + lk;
      w1h[ni][ks] = Wv1h[wi];
      w1l[ni][ks] = Wv1l[wi];
      if (MODE >= 1) {
        w2h[ni][ks] = Wv2h[wi];
        w2l[ni][ks] = Wv2l[wi];
      }
    }

  float bv[2], av[2];
#pragma unroll
  for (int ni = 0; ni < 2; ++ni) {
    int col = ((n0 + ni) << 4) + lrow;
    bv[ni] = bias ? bias[col] : 0.f;
    av[ni] = pa ? pa[col] : 1.f;
  }

#pragma unroll 2
  for (int rg = 0; rg < 8; ++rg) {
    int r = r0 + (rg << 4) + lrow;
    if (r > rows - 1) r = rows - 1;
    size_t off = (size_t)r * 128 + (lk << 3);
    bf16x8 a1h[4], a1l[4], a2f[4];
#pragma unroll
    for (int ks = 0; ks < 4; ++ks) {
      a1h[ks] = *reinterpret_cast<const bf16x8*>(A1h + off + (ks << 5));
      a1l[ks] = *reinterpret_cast<const bf16x8*>(A1l + off + (ks << 5));
      if (MODE >= 1) a2f[ks] = *reinterpret_cast<const bf16x8*>(A2 + off + (ks << 5));
    }
    f32x4 acc[2] = {(f32x4){0.f, 0.f, 0.f, 0.f}, (f32x4){0.f, 0.f, 0.f, 0.f}};
#pragma unroll
    for (int ks = 0; ks < 4; ++ks) {
#pragma unroll
      for (int ni = 0; ni < 2; ++ni) {
        acc[ni] = __builtin_amdgcn_mfma_f32_16x16x32_bf16(a1h[ks], w1h[ni][ks], acc[ni], 0, 0, 0);
        acc[ni] = __builtin_amdgcn_mfma_f32_16x16x32_bf16(a1h[ks], w1l[ni][ks], acc[ni], 0, 0, 0);
        acc[ni] = __builtin_amdgcn_mfma_f32_16x16x32_bf16(a1l[ks], w1h[ni][ks], acc[ni], 0, 0, 0);
        if (MODE >= 1) {
          acc[ni] = __builtin_amdgcn_mfma_f32_16x16x32_bf16(a2f[ks], w2h[ni][ks], acc[ni], 0, 0, 0);
          acc[ni] = __builtin_amdgcn_mfma_f32_16x16x32_bf16(a2f[ks], w2l[ni][ks], acc[ni], 0, 0, 0);
        }
      }
    }
#pragma unroll
    for (int ni = 0; ni < 2; ++ni) {
      int col = ((n0 + ni) << 4) + lrow;
#pragma unroll
      for (int j = 0; j < 4; ++j) {
        int rr = r0 + (rg << 4) + (lk << 2) + j;
        if (rr < rows) {
          float xv = acc[ni][j] + bv[ni];
          if (pa) xv = xv > 0.f ? xv : av[ni] * xv;
          if (MODE == 2) Cf[(size_t)rr * 128 + col] = xv;
          else           Cb[(size_t)rr * 128 + col] = f2bf(xv);
        }
      }
    }
  }
}

// ---------------- mean pool over sorted batch (fp32) ----------------

__device__ __forceinline__ int lower_bound_dev(const int* __restrict__ arr, int n, int val) {
  int lo = 0, hi = n;
  while (lo < hi) {
    int mid = (lo + hi) >> 1;
    if (arr[mid] < val) lo = mid + 1; else hi = mid;
  }
  return lo;
}

__global__ __launch_bounds__(128) void pool_mean(const float* __restrict__ H,
                                                 const int* __restrict__ batch,
                                                 float* __restrict__ pooled) {
  int g = blockIdx.x;
  int t = threadIdx.x;
  int start = lower_bound_dev(batch, NN, g);
  int end = lower_bound_dev(batch, NN, g + 1);
  float acc = 0.f;
  for (int r = start; r < end; ++r) acc += H[(size_t)r * 128 + t];
  int c = end - start;
  float inv = 1.f / (float)(c > 0 ? c : 1);
  pooled[g * 128 + t] = acc * inv;
}

// ---------------- fingerprint head (fp32) ----------------

__global__ __launch_bounds__(128) void fp_head(const float* __restrict__ fp,
                                               const float* __restrict__ Wfp,
                                               const float* __restrict__ bfp,
                                               const float* __restrict__ afp,
                                               float* __restrict__ femb) {
  __shared__ __align__(16) float fs[FPD];
  int g = blockIdx.x;
  int j = threadIdx.x;
  for (int i = j; i < FPD; i += 128) fs[i] = fp[g * FPD + i];
  __syncthreads();
  float acc = bfp[j];
  for (int k = 0; k < FPD; ++k) acc += fs[k] * Wfp[k * 128 + j];
  float a = afp[j];
  femb[g * 128 + j] = acc > 0.f ? acc : a * acc;
}

// ---------------- final ----------------

__global__ __launch_bounds__(64) void final_out(const float* __restrict__ pooled,
                                                const float* __restrict__ femb,
                                                const float* __restrict__ Wp,
                                                const float* __restrict__ bp,
                                                float* __restrict__ out) {
  int g = blockIdx.x;
  int t = threadIdx.x;
  float acc = 0.f;
  for (int i = t; i < 128; i += 64)
    acc += pooled[g * 128 + i] * Wp[i] + femb[g * 128 + i] * Wp[128 + i];
  for (int off = 32; off > 0; off >>= 1) acc += __shfl_down(acc, off);
  if (t == 0) out[g] = acc + bp[0];
}

// ---------------- launch ----------------

extern "C" void kernel_launch(void* const* d_in, const int* in_sizes, int n_in,
                              void* d_out, int out_size, void* d_ws, size_t ws_size,
                              hipStream_t stream) {
  const float* x      = (const float*)d_in[0];
  const float* fp     = (const float*)d_in[1];
  const int*   ei     = (const int*)d_in[2];
  const int*   batch  = (const int*)d_in[3];
  const float* W_pre  = (const float*)d_in[4];
  const float* b_pre  = (const float*)d_in[5];
  const float* a_pre  = (const float*)d_in[6];
  const float* Wl1    = (const float*)d_in[7];
  const float* bl1    = (const float*)d_in[8];
  const float* Wr1    = (const float*)d_in[9];
  const float* a1     = (const float*)d_in[10];
  const float* Wl2    = (const float*)d_in[11];
  const float* bl2    = (const float*)d_in[12];
  const float* Wr2    = (const float*)d_in[13];
  const float* a2     = (const float*)d_in[14];
  const float* W_fp   = (const float*)d_in[15];
  const float* b_fp   = (const float*)d_in[16];
  const float* a_fp   = (const float*)d_in[17];
  const float* W_post = (const float*)d_in[18];
  const float* b_post = (const float*)d_in[19];

  const int* src = ei;
  const int* dst = ei + NE;

  const size_t NBUF = (size_t)NN * 128;
  ushort* buf0 = (ushort*)d_ws;          // x_hi -> agg_hi
  ushort* buf1 = buf0 + NBUF;            // x_lo -> agg_lo
  ushort* buf2 = buf1 + NBUF;            // h0
  ushort* buf3 = buf2 + NBUF;            // h1
  float*  h2f  = (float*)(buf3 + NBUF);  // h2 fp32
  ushort* Wth  = (ushort*)(h2f + NBUF);  // 5*16384
  ushort* Wtl  = Wth + 5 * 16384;        // 5*16384
  int* cnt     = (int*)(Wtl + 5 * 16384);
  int* rowptr  = cnt + NN;               // NN+1 (pad)
  int* bsums   = rowptr + NN + 4;        // 128
  int* partial = bsums + 128;            // NN
  int* colsA   = partial + NN;           // NE
  int* bcnt    = colsA + NE;             // NBUK (pad to 4)
  uint2* bbuf  = (uint2*)(bcnt + ((NBUK + 3) & ~3));  // NBUK*BCAP*8B = 16MB
  float* pooled = (float*)(bbuf + (size_t)NBUK * BCAP);
  float* femb   = pooled + NG * 128;

  // --- bucketed CSR build (dst -> srcs) ---
  hipMemsetAsync(bcnt, 0, NBUK * sizeof(int), stream);
  bucket_scatter<<<(NE + EPB - 1) / EPB, 256, 0, stream>>>(src, dst, bcnt, bbuf, NE);
  bucket_hist<<<NBUK, 256, 0, stream>>>(bcnt, bbuf, cnt);
  int nb = (NN + 1023) / 1024;  // 98
  scan1_kernel<<<nb, 256, 0, stream>>>(cnt, partial, bsums, NN);
  scan2_kernel<<<1, 256, 0, stream>>>(bsums, nb);
  scan3_kernel<<<(NN + 255) / 256, 256, 0, stream>>>(partial, bsums, rowptr, NN);
  bucket_place<<<NBUK, 256, 0, stream>>>(bcnt, bbuf, rowptr, colsA);

  // --- conversions ---
  cvt_x_split<<<(NN * 128 / 4 + 255) / 256, 256, 0, stream>>>(x, buf0, buf1, NN * 128 / 4);
  cvt_w10<<<(5 * 16384 + 255) / 256, 256, 0, stream>>>(W_pre, Wl1, Wr1, Wl2, Wr2, Wth, Wtl);

  const ushort* Wh_pre = Wth;
  const ushort* Wh_l1  = Wth + 16384;
  const ushort* Wh_r1  = Wth + 32768;
  const ushort* Wh_l2  = Wth + 49152;
  const ushort* Wh_r2  = Wth + 65536;
  const ushort* Wl_pre = Wtl;
  const ushort* Wl_l1  = Wtl + 16384;
  const ushort* Wl_r1  = Wtl + 32768;
  const ushort* Wl_l2  = Wtl + 49152;
  const ushort* Wl_r2  = Wtl + 65536;

  int gGemm = (NN + 127) / 128;  // 782

  // pre_mp: h0 = prelu(x@W_pre + b_pre) -> buf2
  gemm_mfma<0><<<gGemm, 256, 0, stream>>>(buf0, buf1, nullptr, Wh_pre, Wl_pre, nullptr,
                                          nullptr, b_pre, a_pre, buf2, nullptr, NN);

  // conv1: agg(h0) -> buf0/buf1; h1 = prelu(agg@Wl1 + h0@Wr1 + bl1) -> buf3
  agg_bf16<<<NN / 4, 256, 0, stream>>>(buf2, rowptr, colsA, buf0, buf1);
  gemm_mfma<1><<<gGemm, 256, 0, stream>>>(buf0, buf1, buf2, Wh_l1, Wl_l1, Wh_r1, Wl_r1,
                                          bl1, a1, buf3, nullptr, NN);

  // conv2: agg(h1) -> buf0/buf1; h2 = prelu(agg@Wl2 + h1@Wr2 + bl2) -> h2f (fp32)
  agg_bf16<<<NN / 4, 256, 0, stream>>>(buf3, rowptr, colsA, buf0, buf1);
  gemm_mfma<2><<<gGemm, 256, 0, stream>>>(buf0, buf1, buf3, Wh_l2, Wl_l2, Wh_r2, Wl_r2,
                                          bl2, a2, nullptr, h2f, NN);

  // pool + heads
  pool_mean<<<NG, 128, 0, stream>>>(h2f, batch, pooled);
  fp_head<<<NG, 128, 0, stream>>>(fp, W_fp, b_fp, a_fp, femb);
  final_out<<<NG, 64, 0, stream>>>(pooled, femb, W_post, b_post, (float*)d_out);
}

// Round 7
// 450.533 us; speedup vs baseline: 2.3252x; 1.1533x over previous
//
#include <hip/hip_runtime.h>

#define NN 100000
#define NE 1600000
#define NG 512
#define HID 128
#define FPD 2048
#define BSHIFT 8
#define NBUK ((NN + 255) >> 8)   // 391
#define BCAP 5120
#define EPB 4096
#define EPT 16

typedef _Float16 f16;
typedef __attribute__((ext_vector_type(8))) _Float16 f16x8;
typedef __attribute__((ext_vector_type(4))) float f32x4;

// ---------------- bucketed CSR build ----------------

__global__ __launch_bounds__(256) void bucket_scatter(const int* __restrict__ src,
                                                      const int* __restrict__ dst,
                                                      int* __restrict__ bcnt,
                                                      uint2* __restrict__ bbuf, int E) {
  __shared__ int hist[NBUK];
  __shared__ int gbase[NBUK];
  __shared__ int lbase[NBUK + 1];
  __shared__ int sc[2][512];
  __shared__ uint2 stage[EPB];
  int t = threadIdx.x;
  int e0 = blockIdx.x * EPB;
  for (int i = t; i < NBUK; i += 256) hist[i] = 0;
  __syncthreads();

  int myb[EPT], myoff[EPT];
  uint2 myp[EPT];
#pragma unroll
  for (int u = 0; u < EPT; ++u) {
    int e = e0 + u * 256 + t;
    myb[u] = -1;
    if (e < E) {
      int d = dst[e];
      int b = d >> BSHIFT;
      myp[u] = make_uint2((uint)d, (uint)src[e]);
      myb[u] = b;
      myoff[u] = atomicAdd(&hist[b], 1);
    }
  }
  __syncthreads();

  sc[0][t] = (t < NBUK) ? hist[t] : 0;
  sc[0][t + 256] = (t + 256 < NBUK) ? hist[t + 256] : 0;
  int pp = 0;
  for (int off = 1; off < 512; off <<= 1) {
    __syncthreads();
    int a0 = sc[pp][t] + ((t >= off) ? sc[pp][t - off] : 0);
    int a1 = sc[pp][t + 256] + ((t + 256 >= off) ? sc[pp][t + 256 - off] : 0);
    sc[1 - pp][t] = a0;
    sc[1 - pp][t + 256] = a1;
    pp = 1 - pp;
  }
  __syncthreads();
  if (t < NBUK) lbase[t] = (t == 0) ? 0 : sc[pp][t - 1];
  if (t + 256 < NBUK) lbase[t + 256] = sc[pp][t + 255];
  if (t == 0) lbase[NBUK] = sc[pp][NBUK - 1];
  for (int i = t; i < NBUK; i += 256)
    if (hist[i] > 0) gbase[i] = atomicAdd(&bcnt[i], hist[i]);
  __syncthreads();

#pragma unroll
  for (int u = 0; u < EPT; ++u)
    if (myb[u] >= 0) stage[lbase[myb[u]] + myoff[u]] = myp[u];
  __syncthreads();

  int total = lbase[NBUK];
  for (int j = t; j < total; j += 256) {
    int lo = 0, hi = NBUK - 1;
    while (lo < hi) {
      int mid = (lo + hi + 1) >> 1;
      if (lbase[mid] <= j) lo = mid; else hi = mid - 1;
    }
    bbuf[(size_t)lo * BCAP + gbase[lo] + (j - lbase[lo])] = stage[j];
  }
}

__global__ __launch_bounds__(256) void bucket_hist(const int* __restrict__ bcnt,
                                                   const uint2* __restrict__ bbuf,
                                                   int* __restrict__ cnt) {
  __shared__ int h[256];
  int b = blockIdx.x, t = threadIdx.x;
  h[t] = 0;
  __syncthreads();
  int n = bcnt[b];
  const uint2* bb = bbuf + (size_t)b * BCAP;
  for (int e = t; e < n; e += 256) atomicAdd(&h[bb[e].x & 255], 1);
  __syncthreads();
  int node = (b << BSHIFT) + t;
  if (node < NN) cnt[node] = h[t];
}

__global__ __launch_bounds__(256) void scan1_kernel(const int* __restrict__ cnt,
                                                    int* __restrict__ partial,
                                                    int* __restrict__ bsums, int n) {
  __shared__ int lds[256];
  int t = threadIdx.x;
  int base = blockIdx.x * 1024 + t * 4;
  int4 v = make_int4(0, 0, 0, 0);
  if (base + 3 < n) {
    v = *reinterpret_cast<const int4*>(&cnt[base]);
  } else {
    if (base     < n) v.x = cnt[base];
    if (base + 1 < n) v.y = cnt[base + 1];
    if (base + 2 < n) v.z = cnt[base + 2];
    if (base + 3 < n) v.w = cnt[base + 3];
  }
  int s = v.x + v.y + v.z + v.w;
  lds[t] = s;
  __syncthreads();
  for (int off = 1; off < 256; off <<= 1) {
    int add = (t >= off) ? lds[t - off] : 0;
    __syncthreads();
    lds[t] += add;
    __syncthreads();
  }
  int run = lds[t] - s;
  run += v.x; if (base     < n) partial[base]     = run;
  run += v.y; if (base + 1 < n) partial[base + 1] = run;
  run += v.z; if (base + 2 < n) partial[base + 2] = run;
  run += v.w; if (base + 3 < n) partial[base + 3] = run;
  if (t == 255) bsums[blockIdx.x] = lds[255];
}

__global__ __launch_bounds__(256) void scan2_kernel(int* __restrict__ bsums, int nb) {
  __shared__ int lds[256];
  int t = threadIdx.x;
  int s = (t < nb) ? bsums[t] : 0;
  lds[t] = s;
  __syncthreads();
  for (int off = 1; off < 256; off <<= 1) {
    int add = (t >= off) ? lds[t - off] : 0;
    __syncthreads();
    lds[t] += add;
    __syncthreads();
  }
  if (t < nb) bsums[t] = lds[t] - s;
}

__global__ __launch_bounds__(256) void scan3_kernel(const int* __restrict__ partial,
                                                    const int* __restrict__ bsums,
                                                    int* __restrict__ rowptr, int n) {
  int i = blockIdx.x * 256 + threadIdx.x;
  if (i == 0) rowptr[0] = 0;
  if (i < n) rowptr[i + 1] = partial[i] + bsums[i >> 10];
}

__global__ __launch_bounds__(256) void bucket_place(const int* __restrict__ bcnt,
                                                    const uint2* __restrict__ bbuf,
                                                    const int* __restrict__ rowptr,
                                                    int* __restrict__ cols) {
  __shared__ int cur[256];
  int b = blockIdx.x, t = threadIdx.x;
  int node = (b << BSHIFT) + t;
  cur[t] = rowptr[node < NN ? node : NN];
  __syncthreads();
  int n = bcnt[b];
  const uint2* bb = bbuf + (size_t)b * BCAP;
  for (int e = t; e < n; e += 256) {
    uint2 p = bb[e];
    int pos = atomicAdd(&cur[p.x & 255], 1);
    cols[pos] = (int)p.y;
  }
}

// ---------------- conversions ----------------

__global__ __launch_bounds__(256) void cvt_x_f16(const float* __restrict__ x,
                                                 f16* __restrict__ xh, int n4) {
  int i = blockIdx.x * 256 + threadIdx.x;
  if (i < n4) {
    float4 v = *reinterpret_cast<const float4*>(&x[i * 4]);
    union { uint2 u; f16 h[4]; } o;
    o.h[0] = (f16)v.x; o.h[1] = (f16)v.y; o.h[2] = (f16)v.z; o.h[3] = (f16)v.w;
    *reinterpret_cast<uint2*>(&xh[i * 4]) = o.u;
  }
}

// transpose+convert 5 [128][128] weights: Wt[w][j][k] = W[k][j]
__global__ __launch_bounds__(256) void cvt_w5(const float* __restrict__ w0,
                                              const float* __restrict__ w1,
                                              const float* __restrict__ w2,
                                              const float* __restrict__ w3,
                                              const float* __restrict__ w4,
                                              f16* __restrict__ out) {
  int idx = blockIdx.x * 256 + threadIdx.x;  // 5*16384
  if (idx >= 5 * 16384) return;
  int w = idx >> 14, rem = idx & 16383;
  int j = rem >> 7, k = rem & 127;
  const float* W = (w == 0) ? w0 : (w == 1) ? w1 : (w == 2) ? w2 : (w == 3) ? w3 : w4;
  out[idx] = (f16)W[k * 128 + j];
}

// ---------------- aggregation (fp16 in/out, fp32 accum) ----------------

__global__ __launch_bounds__(256) void agg_f16(const f16* __restrict__ H,
                                               const int* __restrict__ rowptr,
                                               const int* __restrict__ cols,
                                               f16* __restrict__ out) {
  int node = blockIdx.x * 4 + (threadIdx.x >> 6);
  int lane = threadIdx.x & 63;
  int s = rowptr[node], e = rowptr[node + 1];
  float a0 = 0.f, a1 = 0.f;
  union { uint u; f16 h[2]; } cv;
  int i = s;
  for (; i + 3 < e; i += 4) {
    int c0 = cols[i], c1 = cols[i + 1], c2 = cols[i + 2], c3 = cols[i + 3];
    uint u0 = *reinterpret_cast<const uint*>(&H[(size_t)c0 * 128 + lane * 2]);
    uint u1 = *reinterpret_cast<const uint*>(&H[(size_t)c1 * 128 + lane * 2]);
    uint u2 = *reinterpret_cast<const uint*>(&H[(size_t)c2 * 128 + lane * 2]);
    uint u3 = *reinterpret_cast<const uint*>(&H[(size_t)c3 * 128 + lane * 2]);
    cv.u = u0; a0 += (float)cv.h[0]; a1 += (float)cv.h[1];
    cv.u = u1; a0 += (float)cv.h[0]; a1 += (float)cv.h[1];
    cv.u = u2; a0 += (float)cv.h[0]; a1 += (float)cv.h[1];
    cv.u = u3; a0 += (float)cv.h[0]; a1 += (float)cv.h[1];
  }
  for (; i < e; ++i) {
    cv.u = *reinterpret_cast<const uint*>(&H[(size_t)cols[i] * 128 + lane * 2]);
    a0 += (float)cv.h[0]; a1 += (float)cv.h[1];
  }
  union { uint u; f16 h[2]; } pk;
  pk.h[0] = (f16)a0; pk.h[1] = (f16)a1;
  *reinterpret_cast<uint*>(&out[(size_t)node * 128 + lane * 2]) = pk.u;
}

// ---------------- fp16 MFMA GEMM, W-stationary, dbuf A prefetch ----------------
// MODE 0: C = prelu(A1@W1 + bias)           (f16 out)
// MODE 1: C = prelu(A1@W1 + A2@W2 + bias)   (f16 out)
// MODE 2: same as 1, fp32 out
// 256 thr = 4 waves; block = 128 rows; wave w owns cols [32w,32w+32).
// Independent accumulator per term -> 4-deep chains; A double-buffered.

template <int MODE>
__global__ __launch_bounds__(256) void gemm_f16(const f16* __restrict__ A1,
                                                const f16* __restrict__ A2,
                                                const f16* __restrict__ W1t,
                                                const f16* __restrict__ W2t,
                                                const float* __restrict__ bias,
                                                const float* __restrict__ pa,
                                                f16* __restrict__ Ch,
                                                float* __restrict__ Cf, int rows) {
  int t = threadIdx.x;
  int wave = t >> 6, lane = t & 63;
  int lrow = lane & 15, lk = lane >> 4;
  int r0 = blockIdx.x * 128;
  int n0 = wave << 1;

  const f16x8* Wv1 = reinterpret_cast<const f16x8*>(W1t);
  const f16x8* Wv2 = reinterpret_cast<const f16x8*>(W2t);

  f16x8 w1[2][4], w2[2][4];
#pragma unroll
  for (int ni = 0; ni < 2; ++ni)
#pragma unroll
    for (int ks = 0; ks < 4; ++ks) {
      int wi = ((((n0 + ni) << 4) + lrow) << 4) + (ks << 2) + lk;
      w1[ni][ks] = Wv1[wi];
      if (MODE >= 1) w2[ni][ks] = Wv2[wi];
    }

  float bv[2], av[2];
#pragma unroll
  for (int ni = 0; ni < 2; ++ni) {
    int col = ((n0 + ni) << 4) + lrow;
    bv[ni] = bias ? bias[col] : 0.f;
    av[ni] = pa ? pa[col] : 1.f;
  }

  f16x8 aA[2][4], aB[2][4];
  {
    int r = r0 + lrow;
    if (r > rows - 1) r = rows - 1;
    size_t off = (size_t)r * 128 + (lk << 3);
#pragma unroll
    for (int ks = 0; ks < 4; ++ks) {
      aA[0][ks] = *reinterpret_cast<const f16x8*>(A1 + off + (ks << 5));
      if (MODE >= 1) aB[0][ks] = *reinterpret_cast<const f16x8*>(A2 + off + (ks << 5));
    }
  }

#pragma unroll
  for (int rg = 0; rg < 8; ++rg) {
    int cur = rg & 1, nxt = cur ^ 1;
    if (rg < 7) {
      int rn = r0 + ((rg + 1) << 4) + lrow;
      if (rn > rows - 1) rn = rows - 1;
      size_t offn = (size_t)rn * 128 + (lk << 3);
#pragma unroll
      for (int ks = 0; ks < 4; ++ks) {
        aA[nxt][ks] = *reinterpret_cast<const f16x8*>(A1 + offn + (ks << 5));
        if (MODE >= 1) aB[nxt][ks] = *reinterpret_cast<const f16x8*>(A2 + offn + (ks << 5));
      }
    }
    f32x4 acc1[2] = {(f32x4){0.f, 0.f, 0.f, 0.f}, (f32x4){0.f, 0.f, 0.f, 0.f}};
    f32x4 acc2[2] = {(f32x4){0.f, 0.f, 0.f, 0.f}, (f32x4){0.f, 0.f, 0.f, 0.f}};
#pragma unroll
    for (int ks = 0; ks < 4; ++ks) {
#pragma unroll
      for (int ni = 0; ni < 2; ++ni) {
        acc1[ni] = __builtin_amdgcn_mfma_f32_16x16x32_f16(aA[cur][ks], w1[ni][ks], acc1[ni], 0, 0, 0);
        if (MODE >= 1)
          acc2[ni] = __builtin_amdgcn_mfma_f32_16x16x32_f16(aB[cur][ks], w2[ni][ks], acc2[ni], 0, 0, 0);
      }
    }
    // epilogue: C/D layout col=lane&15, row_in_tile=(lane>>4)*4+j
#pragma unroll
    for (int ni = 0; ni < 2; ++ni) {
      int col = ((n0 + ni) << 4) + lrow;
#pragma unroll
      for (int j = 0; j < 4; ++j) {
        int rr = r0 + (rg << 4) + (lk << 2) + j;
        if (rr < rows) {
          float xv = acc1[ni][j] + bv[ni];
          if (MODE >= 1) xv += acc2[ni][j];
          if (pa) xv = xv > 0.f ? xv : av[ni] * xv;
          if (MODE == 2) Cf[(size_t)rr * 128 + col] = xv;
          else           Ch[(size_t)rr * 128 + col] = (f16)xv;
        }
      }
    }
  }
}

// ---------------- mean pool over sorted batch (fp32) ----------------

__device__ __forceinline__ int lower_bound_dev(const int* __restrict__ arr, int n, int val) {
  int lo = 0, hi = n;
  while (lo < hi) {
    int mid = (lo + hi) >> 1;
    if (arr[mid] < val) lo = mid + 1; else hi = mid;
  }
  return lo;
}

__global__ __launch_bounds__(128) void pool_mean(const float* __restrict__ H,
                                                 const int* __restrict__ batch,
                                                 float* __restrict__ pooled) {
  int g = blockIdx.x;
  int t = threadIdx.x;
  int start = lower_bound_dev(batch, NN, g);
  int end = lower_bound_dev(batch, NN, g + 1);
  float acc = 0.f;
  for (int r = start; r < end; ++r) acc += H[(size_t)r * 128 + t];
  int c = end - start;
  float inv = 1.f / (float)(c > 0 ? c : 1);
  pooled[g * 128 + t] = acc * inv;
}

// ---------------- fingerprint head (fp32) ----------------

__global__ __launch_bounds__(128) void fp_head(const float* __restrict__ fp,
                                               const float* __restrict__ Wfp,
                                               const float* __restrict__ bfp,
                                               const float* __restrict__ afp,
                                               float* __restrict__ femb) {
  __shared__ __align__(16) float fs[FPD];
  int g = blockIdx.x;
  int j = threadIdx.x;
  for (int i = j; i < FPD; i += 128) fs[i] = fp[g * FPD + i];
  __syncthreads();
  float acc = bfp[j];
  for (int k = 0; k < FPD; ++k) acc += fs[k] * Wfp[k * 128 + j];
  float a = afp[j];
  femb[g * 128 + j] = acc > 0.f ? acc : a * acc;
}

// ---------------- final ----------------

__global__ __launch_bounds__(64) void final_out(const float* __restrict__ pooled,
                                                const float* __restrict__ femb,
                                                const float* __restrict__ Wp,
                                                const float* __restrict__ bp,
                                                float* __restrict__ out) {
  int g = blockIdx.x;
  int t = threadIdx.x;
  float acc = 0.f;
  for (int i = t; i < 128; i += 64)
    acc += pooled[g * 128 + i] * Wp[i] + femb[g * 128 + i] * Wp[128 + i];
  for (int off = 32; off > 0; off >>= 1) acc += __shfl_down(acc, off);
  if (t == 0) out[g] = acc + bp[0];
}

// ---------------- launch ----------------

extern "C" void kernel_launch(void* const* d_in, const int* in_sizes, int n_in,
                              void* d_out, int out_size, void* d_ws, size_t ws_size,
                              hipStream_t stream) {
  const float* x      = (const float*)d_in[0];
  const float* fp     = (const float*)d_in[1];
  const int*   ei     = (const int*)d_in[2];
  const int*   batch  = (const int*)d_in[3];
  const float* W_pre  = (const float*)d_in[4];
  const float* b_pre  = (const float*)d_in[5];
  const float* a_pre  = (const float*)d_in[6];
  const float* Wl1    = (const float*)d_in[7];
  const float* bl1    = (const float*)d_in[8];
  const float* Wr1    = (const float*)d_in[9];
  const float* a1     = (const float*)d_in[10];
  const float* Wl2    = (const float*)d_in[11];
  const float* bl2    = (const float*)d_in[12];
  const float* Wr2    = (const float*)d_in[13];
  const float* a2     = (const float*)d_in[14];
  const float* W_fp   = (const float*)d_in[15];
  const float* b_fp   = (const float*)d_in[16];
  const float* a_fp   = (const float*)d_in[17];
  const float* W_post = (const float*)d_in[18];
  const float* b_post = (const float*)d_in[19];

  const int* src = ei;
  const int* dst = ei + NE;

  const size_t NBUF = (size_t)NN * 128;
  f16* buf0 = (f16*)d_ws;                // x_f16 -> agg2
  f16* buf1 = buf0 + NBUF;               // agg1
  f16* buf2 = buf1 + NBUF;               // h0
  f16* buf3 = buf2 + NBUF;               // h1
  float* h2f = (float*)(buf3 + NBUF);    // h2 fp32
  f16* Wt    = (f16*)(h2f + NBUF);       // 5*16384
  int* cnt     = (int*)(Wt + 5 * 16384);
  int* rowptr  = cnt + NN;               // NN+1 (pad)
  int* bsums   = rowptr + NN + 4;        // 128
  int* partial = bsums + 128;            // NN
  int* colsA   = partial + NN;           // NE
  int* bcnt    = colsA + NE;             // NBUK (pad to 4)
  uint2* bbuf  = (uint2*)(bcnt + ((NBUK + 3) & ~3));  // 16MB
  float* pooled = (float*)(bbuf + (size_t)NBUK * BCAP);
  float* femb   = pooled + NG * 128;

  // --- bucketed CSR build (dst -> srcs) ---
  hipMemsetAsync(bcnt, 0, NBUK * sizeof(int), stream);
  bucket_scatter<<<(NE + EPB - 1) / EPB, 256, 0, stream>>>(src, dst, bcnt, bbuf, NE);
  bucket_hist<<<NBUK, 256, 0, stream>>>(bcnt, bbuf, cnt);
  int nb = (NN + 1023) / 1024;  // 98
  scan1_kernel<<<nb, 256, 0, stream>>>(cnt, partial, bsums, NN);
  scan2_kernel<<<1, 256, 0, stream>>>(bsums, nb);
  scan3_kernel<<<(NN + 255) / 256, 256, 0, stream>>>(partial, bsums, rowptr, NN);
  bucket_place<<<NBUK, 256, 0, stream>>>(bcnt, bbuf, rowptr, colsA);

  // --- conversions ---
  cvt_x_f16<<<(NN * 128 / 4 + 255) / 256, 256, 0, stream>>>(x, buf0, NN * 128 / 4);
  cvt_w5<<<(5 * 16384 + 255) / 256, 256, 0, stream>>>(W_pre, Wl1, Wr1, Wl2, Wr2, Wt);

  const f16* Wt_pre = Wt;
  const f16* Wt_l1  = Wt + 16384;
  const f16* Wt_r1  = Wt + 32768;
  const f16* Wt_l2  = Wt + 49152;
  const f16* Wt_r2  = Wt + 65536;

  int gGemm = (NN + 127) / 128;  // 782

  // pre_mp: h0 = prelu(x@W_pre + b_pre) -> buf2
  gemm_f16<0><<<gGemm, 256, 0, stream>>>(buf0, nullptr, Wt_pre, nullptr,
                                         b_pre, a_pre, buf2, nullptr, NN);

  // conv1: agg(h0) -> buf1; h1 = prelu(agg@Wl1 + h0@Wr1 + bl1) -> buf3
  agg_f16<<<NN / 4, 256, 0, stream>>>(buf2, rowptr, colsA, buf1);
  gemm_f16<1><<<gGemm, 256, 0, stream>>>(buf1, buf2, Wt_l1, Wt_r1,
                                         bl1, a1, buf3, nullptr, NN);

  // conv2: agg(h1) -> buf0; h2 = prelu(agg@Wl2 + h1@Wr2 + bl2) -> h2f (fp32)
  agg_f16<<<NN / 4, 256, 0, stream>>>(buf3, rowptr, colsA, buf0);
  gemm_f16<2><<<gGemm, 256, 0, stream>>>(buf0, buf3, Wt_l2, Wt_r2,
                                         bl2, a2, nullptr, h2f, NN);

  // pool + heads
  pool_mean<<<NG, 128, 0, stream>>>(h2f, batch, pooled);
  fp_head<<<NG, 128, 0, stream>>>(fp, W_fp, b_fp, a_fp, femb);
  final_out<<<NG, 64, 0, stream>>>(pooled, femb, W_post, b_post, (float*)d_out);
}

// Round 8
// 362.929 us; speedup vs baseline: 2.8865x; 1.2414x over previous
//
#include <hip/hip_runtime.h>

#define NN 100000
#define NE 1600000
#define NG 512
#define HID 128
#define FPD 2048
#define BSHIFT 8
#define NBUK ((NN + 255) >> 8)   // 391
#define BCAP 5120
#define EPB 4096
#define EPT 16

typedef _Float16 f16;
typedef __attribute__((ext_vector_type(8))) _Float16 f16x8;
typedef __attribute__((ext_vector_type(4))) float f32x4;

// ---------------- bucketed CSR build ----------------

__global__ __launch_bounds__(256) void bucket_scatter(const int* __restrict__ src,
                                                      const int* __restrict__ dst,
                                                      int* __restrict__ bcnt,
                                                      uint2* __restrict__ bbuf, int E) {
  __shared__ int hist[NBUK];
  __shared__ int gbase[NBUK];
  __shared__ int lbase[NBUK + 1];
  __shared__ int sc[2][512];
  __shared__ uint2 stage[EPB];
  int t = threadIdx.x;
  int e0 = blockIdx.x * EPB;
  for (int i = t; i < NBUK; i += 256) hist[i] = 0;
  __syncthreads();

  int myb[EPT], myoff[EPT];
  uint2 myp[EPT];
#pragma unroll
  for (int u = 0; u < EPT; ++u) {
    int e = e0 + u * 256 + t;
    myb[u] = -1;
    if (e < E) {
      int d = dst[e];
      int b = d >> BSHIFT;
      myp[u] = make_uint2((uint)d, (uint)src[e]);
      myb[u] = b;
      myoff[u] = atomicAdd(&hist[b], 1);
    }
  }
  __syncthreads();

  sc[0][t] = (t < NBUK) ? hist[t] : 0;
  sc[0][t + 256] = (t + 256 < NBUK) ? hist[t + 256] : 0;
  int pp = 0;
  for (int off = 1; off < 512; off <<= 1) {
    __syncthreads();
    int a0 = sc[pp][t] + ((t >= off) ? sc[pp][t - off] : 0);
    int a1 = sc[pp][t + 256] + ((t + 256 >= off) ? sc[pp][t + 256 - off] : 0);
    sc[1 - pp][t] = a0;
    sc[1 - pp][t + 256] = a1;
    pp = 1 - pp;
  }
  __syncthreads();
  if (t < NBUK) lbase[t] = (t == 0) ? 0 : sc[pp][t - 1];
  if (t + 256 < NBUK) lbase[t + 256] = sc[pp][t + 255];
  if (t == 0) lbase[NBUK] = sc[pp][NBUK - 1];
  for (int i = t; i < NBUK; i += 256)
    if (hist[i] > 0) gbase[i] = atomicAdd(&bcnt[i], hist[i]);
  __syncthreads();

#pragma unroll
  for (int u = 0; u < EPT; ++u)
    if (myb[u] >= 0) stage[lbase[myb[u]] + myoff[u]] = myp[u];
  __syncthreads();

  int total = lbase[NBUK];
  for (int j = t; j < total; j += 256) {
    int lo = 0, hi = NBUK - 1;
    while (lo < hi) {
      int mid = (lo + hi + 1) >> 1;
      if (lbase[mid] <= j) lo = mid; else hi = mid - 1;
    }
    bbuf[(size_t)lo * BCAP + gbase[lo] + (j - lbase[lo])] = stage[j];
  }
}

__global__ __launch_bounds__(256) void bucket_hist(const int* __restrict__ bcnt,
                                                   const uint2* __restrict__ bbuf,
                                                   int* __restrict__ cnt) {
  __shared__ int h[256];
  int b = blockIdx.x, t = threadIdx.x;
  h[t] = 0;
  __syncthreads();
  int n = bcnt[b];
  const uint2* bb = bbuf + (size_t)b * BCAP;
  for (int e = t; e < n; e += 256) atomicAdd(&h[bb[e].x & 255], 1);
  __syncthreads();
  int node = (b << BSHIFT) + t;
  if (node < NN) cnt[node] = h[t];
}

__global__ __launch_bounds__(256) void scan1_kernel(const int* __restrict__ cnt,
                                                    int* __restrict__ partial,
                                                    int* __restrict__ bsums, int n) {
  __shared__ int lds[256];
  int t = threadIdx.x;
  int base = blockIdx.x * 1024 + t * 4;
  int4 v = make_int4(0, 0, 0, 0);
  if (base + 3 < n) {
    v = *reinterpret_cast<const int4*>(&cnt[base]);
  } else {
    if (base     < n) v.x = cnt[base];
    if (base + 1 < n) v.y = cnt[base + 1];
    if (base + 2 < n) v.z = cnt[base + 2];
    if (base + 3 < n) v.w = cnt[base + 3];
  }
  int s = v.x + v.y + v.z + v.w;
  lds[t] = s;
  __syncthreads();
  for (int off = 1; off < 256; off <<= 1) {
    int add = (t >= off) ? lds[t - off] : 0;
    __syncthreads();
    lds[t] += add;
    __syncthreads();
  }
  int run = lds[t] - s;
  run += v.x; if (base     < n) partial[base]     = run;
  run += v.y; if (base + 1 < n) partial[base + 1] = run;
  run += v.z; if (base + 2 < n) partial[base + 2] = run;
  run += v.w; if (base + 3 < n) partial[base + 3] = run;
  if (t == 255) bsums[blockIdx.x] = lds[255];
}

__global__ __launch_bounds__(256) void scan2_kernel(int* __restrict__ bsums, int nb) {
  __shared__ int lds[256];
  int t = threadIdx.x;
  int s = (t < nb) ? bsums[t] : 0;
  lds[t] = s;
  __syncthreads();
  for (int off = 1; off < 256; off <<= 1) {
    int add = (t >= off) ? lds[t - off] : 0;
    __syncthreads();
    lds[t] += add;
    __syncthreads();
  }
  if (t < nb) bsums[t] = lds[t] - s;
}

__global__ __launch_bounds__(256) void scan3_kernel(const int* __restrict__ partial,
                                                    const int* __restrict__ bsums,
                                                    int* __restrict__ rowptr, int n) {
  int i = blockIdx.x * 256 + threadIdx.x;
  if (i == 0) rowptr[0] = 0;
  if (i < n) rowptr[i + 1] = partial[i] + bsums[i >> 10];
}

__global__ __launch_bounds__(256) void bucket_place(const int* __restrict__ bcnt,
                                                    const uint2* __restrict__ bbuf,
                                                    const int* __restrict__ rowptr,
                                                    int* __restrict__ cols) {
  __shared__ int cur[256];
  int b = blockIdx.x, t = threadIdx.x;
  int node = (b << BSHIFT) + t;
  cur[t] = rowptr[node < NN ? node : NN];
  __syncthreads();
  int n = bcnt[b];
  const uint2* bb = bbuf + (size_t)b * BCAP;
  for (int e = t; e < n; e += 256) {
    uint2 p = bb[e];
    int pos = atomicAdd(&cur[p.x & 255], 1);
    cols[pos] = (int)p.y;
  }
}

// ---------------- conversions ----------------

__global__ __launch_bounds__(256) void cvt_f32_f16(const float* __restrict__ x,
                                                   f16* __restrict__ xh, int n4) {
  int i = blockIdx.x * 256 + threadIdx.x;
  if (i < n4) {
    float4 v = *reinterpret_cast<const float4*>(&x[i * 4]);
    union { uint2 u; f16 h[4]; } o;
    o.h[0] = (f16)v.x; o.h[1] = (f16)v.y; o.h[2] = (f16)v.z; o.h[3] = (f16)v.w;
    *reinterpret_cast<uint2*>(&xh[i * 4]) = o.u;
  }
}

// transpose+convert 5 [128][128] weights: Wt[w][j][k] = W[k][j]
__global__ __launch_bounds__(256) void cvt_w5(const float* __restrict__ w0,
                                              const float* __restrict__ w1,
                                              const float* __restrict__ w2,
                                              const float* __restrict__ w3,
                                              const float* __restrict__ w4,
                                              f16* __restrict__ out) {
  int idx = blockIdx.x * 256 + threadIdx.x;  // 5*16384
  if (idx >= 5 * 16384) return;
  int w = idx >> 14, rem = idx & 16383;
  int j = rem >> 7, k = rem & 127;
  const float* W = (w == 0) ? w0 : (w == 1) ? w1 : (w == 2) ? w2 : (w == 3) ? w3 : w4;
  out[idx] = (f16)W[k * 128 + j];
}

// transpose+convert W_fp [2048][128] -> Wfpt[j][k] (128 x 2048)
__global__ __launch_bounds__(256) void cvt_wfp(const float* __restrict__ W,
                                               f16* __restrict__ out) {
  int idx = blockIdx.x * 256 + threadIdx.x;  // 128*2048
  if (idx >= 128 * 2048) return;
  int j = idx >> 11, k = idx & 2047;
  out[idx] = (f16)W[k * 128 + j];
}

// ---------------- aggregation (fp16 in/out, fp32 accum) ----------------

__global__ __launch_bounds__(256) void agg_f16(const f16* __restrict__ H,
                                               const int* __restrict__ rowptr,
                                               const int* __restrict__ cols,
                                               f16* __restrict__ out) {
  int node = blockIdx.x * 4 + (threadIdx.x >> 6);
  int lane = threadIdx.x & 63;
  int s = rowptr[node], e = rowptr[node + 1];
  float a0 = 0.f, a1 = 0.f;
  union { uint u; f16 h[2]; } cv;
  int i = s;
  for (; i + 3 < e; i += 4) {
    int c0 = cols[i], c1 = cols[i + 1], c2 = cols[i + 2], c3 = cols[i + 3];
    uint u0 = *reinterpret_cast<const uint*>(&H[(size_t)c0 * 128 + lane * 2]);
    uint u1 = *reinterpret_cast<const uint*>(&H[(size_t)c1 * 128 + lane * 2]);
    uint u2 = *reinterpret_cast<const uint*>(&H[(size_t)c2 * 128 + lane * 2]);
    uint u3 = *reinterpret_cast<const uint*>(&H[(size_t)c3 * 128 + lane * 2]);
    cv.u = u0; a0 += (float)cv.h[0]; a1 += (float)cv.h[1];
    cv.u = u1; a0 += (float)cv.h[0]; a1 += (float)cv.h[1];
    cv.u = u2; a0 += (float)cv.h[0]; a1 += (float)cv.h[1];
    cv.u = u3; a0 += (float)cv.h[0]; a1 += (float)cv.h[1];
  }
  for (; i < e; ++i) {
    cv.u = *reinterpret_cast<const uint*>(&H[(size_t)cols[i] * 128 + lane * 2]);
    a0 += (float)cv.h[0]; a1 += (float)cv.h[1];
  }
  union { uint u; f16 h[2]; } pk;
  pk.h[0] = (f16)a0; pk.h[1] = (f16)a1;
  *reinterpret_cast<uint*>(&out[(size_t)node * 128 + lane * 2]) = pk.u;
}

// ---------------- fp16 MFMA GEMM, W-stationary, dbuf A prefetch ----------------
// MODE 0: C = prelu(A1@W1 + bias)           (f16 out)
// MODE 1: C = prelu(A1@W1 + A2@W2 + bias)   (f16 out)

template <int MODE>
__global__ __launch_bounds__(256) void gemm_f16(const f16* __restrict__ A1,
                                                const f16* __restrict__ A2,
                                                const f16* __restrict__ W1t,
                                                const f16* __restrict__ W2t,
                                                const float* __restrict__ bias,
                                                const float* __restrict__ pa,
                                                f16* __restrict__ Ch, int rows) {
  int t = threadIdx.x;
  int wave = t >> 6, lane = t & 63;
  int lrow = lane & 15, lk = lane >> 4;
  int r0 = blockIdx.x * 128;
  int n0 = wave << 1;

  const f16x8* Wv1 = reinterpret_cast<const f16x8*>(W1t);
  const f16x8* Wv2 = reinterpret_cast<const f16x8*>(W2t);

  f16x8 w1[2][4], w2[2][4];
#pragma unroll
  for (int ni = 0; ni < 2; ++ni)
#pragma unroll
    for (int ks = 0; ks < 4; ++ks) {
      int wi = ((((n0 + ni) << 4) + lrow) << 4) + (ks << 2) + lk;
      w1[ni][ks] = Wv1[wi];
      if (MODE >= 1) w2[ni][ks] = Wv2[wi];
    }

  float bv[2], av[2];
#pragma unroll
  for (int ni = 0; ni < 2; ++ni) {
    int col = ((n0 + ni) << 4) + lrow;
    bv[ni] = bias ? bias[col] : 0.f;
    av[ni] = pa ? pa[col] : 1.f;
  }

  f16x8 aA[2][4], aB[2][4];
  {
    int r = r0 + lrow;
    if (r > rows - 1) r = rows - 1;
    size_t off = (size_t)r * 128 + (lk << 3);
#pragma unroll
    for (int ks = 0; ks < 4; ++ks) {
      aA[0][ks] = *reinterpret_cast<const f16x8*>(A1 + off + (ks << 5));
      if (MODE >= 1) aB[0][ks] = *reinterpret_cast<const f16x8*>(A2 + off + (ks << 5));
    }
  }

#pragma unroll
  for (int rg = 0; rg < 8; ++rg) {
    int cur = rg & 1, nxt = cur ^ 1;
    if (rg < 7) {
      int rn = r0 + ((rg + 1) << 4) + lrow;
      if (rn > rows - 1) rn = rows - 1;
      size_t offn = (size_t)rn * 128 + (lk << 3);
#pragma unroll
      for (int ks = 0; ks < 4; ++ks) {
        aA[nxt][ks] = *reinterpret_cast<const f16x8*>(A1 + offn + (ks << 5));
        if (MODE >= 1) aB[nxt][ks] = *reinterpret_cast<const f16x8*>(A2 + offn + (ks << 5));
      }
    }
    f32x4 acc1[2] = {(f32x4){0.f, 0.f, 0.f, 0.f}, (f32x4){0.f, 0.f, 0.f, 0.f}};
    f32x4 acc2[2] = {(f32x4){0.f, 0.f, 0.f, 0.f}, (f32x4){0.f, 0.f, 0.f, 0.f}};
#pragma unroll
    for (int ks = 0; ks < 4; ++ks) {
#pragma unroll
      for (int ni = 0; ni < 2; ++ni) {
        acc1[ni] = __builtin_amdgcn_mfma_f32_16x16x32_f16(aA[cur][ks], w1[ni][ks], acc1[ni], 0, 0, 0);
        if (MODE >= 1)
          acc2[ni] = __builtin_amdgcn_mfma_f32_16x16x32_f16(aB[cur][ks], w2[ni][ks], acc2[ni], 0, 0, 0);
      }
    }
#pragma unroll
    for (int ni = 0; ni < 2; ++ni) {
      int col = ((n0 + ni) << 4) + lrow;
#pragma unroll
      for (int j = 0; j < 4; ++j) {
        int rr = r0 + (rg << 4) + (lk << 2) + j;
        if (rr < rows) {
          float xv = acc1[ni][j] + bv[ni];
          if (MODE >= 1) xv += acc2[ni][j];
          if (pa) xv = xv > 0.f ? xv : av[ni] * xv;
          Ch[(size_t)rr * 128 + col] = (f16)xv;
        }
      }
    }
  }
}

// ---------------- fingerprint head: MFMA with K-split ----------------
// grid (16 kchunks, 4 rowblocks); A = fp_f16[512][2048]; Wt = Wfpt[128][2048].
// part[kc][r][col] fp32 partial sums.

__global__ __launch_bounds__(256) void fp_gemm(const f16* __restrict__ A,
                                               const f16* __restrict__ Wt,
                                               float* __restrict__ part) {
  int kc = blockIdx.x;   // 0..15
  int rb = blockIdx.y;   // 0..3
  int t = threadIdx.x;
  int wave = t >> 6, lane = t & 63;
  int lrow = lane & 15, lk = lane >> 4;
  int r0 = rb * 128;
  int n0 = wave << 1;

  const f16x8* Wv = reinterpret_cast<const f16x8*>(Wt);
  const f16x8* Av = reinterpret_cast<const f16x8*>(A);

  f16x8 w[2][4];
#pragma unroll
  for (int ni = 0; ni < 2; ++ni)
#pragma unroll
    for (int ks = 0; ks < 4; ++ks) {
      int j = ((n0 + ni) << 4) + lrow;
      w[ni][ks] = Wv[j * 256 + (kc << 4) + (ks << 2) + lk];
    }

#pragma unroll 2
  for (int rg = 0; rg < 8; ++rg) {
    int r = r0 + (rg << 4) + lrow;
    f16x8 a[4];
#pragma unroll
    for (int ks = 0; ks < 4; ++ks)
      a[ks] = Av[r * 256 + (kc << 4) + (ks << 2) + lk];
    f32x4 acc[2] = {(f32x4){0.f, 0.f, 0.f, 0.f}, (f32x4){0.f, 0.f, 0.f, 0.f}};
#pragma unroll
    for (int ks = 0; ks < 4; ++ks)
#pragma unroll
      for (int ni = 0; ni < 2; ++ni)
        acc[ni] = __builtin_amdgcn_mfma_f32_16x16x32_f16(a[ks], w[ni][ks], acc[ni], 0, 0, 0);
#pragma unroll
    for (int ni = 0; ni < 2; ++ni) {
      int col = ((n0 + ni) << 4) + lrow;
#pragma unroll
      for (int j = 0; j < 4; ++j) {
        int rr = r0 + (rg << 4) + (lk << 2) + j;
        part[((size_t)kc * 512 + rr) * 128 + col] = acc[ni][j];
      }
    }
  }
}

__global__ __launch_bounds__(256) void fp_fin(const float* __restrict__ part,
                                              const float* __restrict__ bfp,
                                              const float* __restrict__ afp,
                                              float* __restrict__ femb) {
  int idx = blockIdx.x * 256 + threadIdx.x;  // 512*128
  if (idx >= 512 * 128) return;
  int j = idx & 127;
  float s = bfp[j];
#pragma unroll
  for (int kc = 0; kc < 16; ++kc) s += part[(size_t)kc * 65536 + idx];
  float a = afp[j];
  femb[idx] = s > 0.f ? s : a * s;
}

// ---------------- mean pool over sorted batch (f16 in, fp32 out) ----------------

__device__ __forceinline__ int lower_bound_dev(const int* __restrict__ arr, int n, int val) {
  int lo = 0, hi = n;
  while (lo < hi) {
    int mid = (lo + hi) >> 1;
    if (arr[mid] < val) lo = mid + 1; else hi = mid;
  }
  return lo;
}

__global__ __launch_bounds__(512) void pool_mean(const f16* __restrict__ H,
                                                 const int* __restrict__ batch,
                                                 float* __restrict__ pooled) {
  __shared__ float red[512];
  int g = blockIdx.x;
  int t = threadIdx.x;
  int col = t & 127, rq = t >> 7;
  int start = lower_bound_dev(batch, NN, g);
  int end = lower_bound_dev(batch, NN, g + 1);
  float acc = 0.f;
  for (int r = start + rq; r < end; r += 4) acc += (float)H[(size_t)r * 128 + col];
  red[t] = acc;
  __syncthreads();
  if (rq == 0) {
    float s = red[col] + red[128 + col] + red[256 + col] + red[384 + col];
    int c = end - start;
    pooled[g * 128 + col] = s / (float)(c > 0 ? c : 1);
  }
}

// ---------------- final ----------------

__global__ __launch_bounds__(64) void final_out(const float* __restrict__ pooled,
                                                const float* __restrict__ femb,
                                                const float* __restrict__ Wp,
                                                const float* __restrict__ bp,
                                                float* __restrict__ out) {
  int g = blockIdx.x;
  int t = threadIdx.x;
  float acc = 0.f;
  for (int i = t; i < 128; i += 64)
    acc += pooled[g * 128 + i] * Wp[i] + femb[g * 128 + i] * Wp[128 + i];
  for (int off = 32; off > 0; off >>= 1) acc += __shfl_down(acc, off);
  if (t == 0) out[g] = acc + bp[0];
}

// ---------------- launch ----------------

extern "C" void kernel_launch(void* const* d_in, const int* in_sizes, int n_in,
                              void* d_out, int out_size, void* d_ws, size_t ws_size,
                              hipStream_t stream) {
  const float* x      = (const float*)d_in[0];
  const float* fp     = (const float*)d_in[1];
  const int*   ei     = (const int*)d_in[2];
  const int*   batch  = (const int*)d_in[3];
  const float* W_pre  = (const float*)d_in[4];
  const float* b_pre  = (const float*)d_in[5];
  const float* a_pre  = (const float*)d_in[6];
  const float* Wl1    = (const float*)d_in[7];
  const float* bl1    = (const float*)d_in[8];
  const float* Wr1    = (const float*)d_in[9];
  const float* a1     = (const float*)d_in[10];
  const float* Wl2    = (const float*)d_in[11];
  const float* bl2    = (const float*)d_in[12];
  const float* Wr2    = (const float*)d_in[13];
  const float* a2     = (const float*)d_in[14];
  const float* W_fp   = (const float*)d_in[15];
  const float* b_fp   = (const float*)d_in[16];
  const float* a_fp   = (const float*)d_in[17];
  const float* W_post = (const float*)d_in[18];
  const float* b_post = (const float*)d_in[19];

  const int* src = ei;
  const int* dst = ei + NE;

  const size_t NBUF = (size_t)NN * 128;
  f16* buf0 = (f16*)d_ws;                // x_f16 -> agg2
  f16* buf1 = buf0 + NBUF;               // agg1
  f16* buf2 = buf1 + NBUF;               // h0 -> h2
  f16* buf3 = buf2 + NBUF;               // h1
  f16* Wt   = buf3 + NBUF;               // 5*16384
  f16* fpb  = Wt + 5 * 16384;            // fp f16: 512*2048
  f16* Wfpt = fpb + 512 * 2048;          // 128*2048
  float* part = (float*)(Wfpt + 128 * 2048);  // 16*512*128 fp32 = 4MB
  int* cnt     = (int*)(part + 16 * 512 * 128);
  int* rowptr  = cnt + NN;               // NN+1 (pad)
  int* bsums   = rowptr + NN + 4;        // 128
  int* partial = bsums + 128;            // NN
  int* colsA   = partial + NN;           // NE
  int* bcnt    = colsA + NE;             // NBUK (pad to 4)
  uint2* bbuf  = (uint2*)(bcnt + ((NBUK + 3) & ~3));  // 16MB
  float* pooled = (float*)(bbuf + (size_t)NBUK * BCAP);
  float* femb   = pooled + NG * 128;

  // --- bucketed CSR build (dst -> srcs) ---
  hipMemsetAsync(bcnt, 0, NBUK * sizeof(int), stream);
  bucket_scatter<<<(NE + EPB - 1) / EPB, 256, 0, stream>>>(src, dst, bcnt, bbuf, NE);
  bucket_hist<<<NBUK, 256, 0, stream>>>(bcnt, bbuf, cnt);
  int nb = (NN + 1023) / 1024;  // 98
  scan1_kernel<<<nb, 256, 0, stream>>>(cnt, partial, bsums, NN);
  scan2_kernel<<<1, 256, 0, stream>>>(bsums, nb);
  scan3_kernel<<<(NN + 255) / 256, 256, 0, stream>>>(partial, bsums, rowptr, NN);
  bucket_place<<<NBUK, 256, 0, stream>>>(bcnt, bbuf, rowptr, colsA);

  // --- conversions ---
  cvt_f32_f16<<<(NN * 128 / 4 + 255) / 256, 256, 0, stream>>>(x, buf0, NN * 128 / 4);
  cvt_w5<<<(5 * 16384 + 255) / 256, 256, 0, stream>>>(W_pre, Wl1, Wr1, Wl2, Wr2, Wt);
  cvt_f32_f16<<<(512 * 2048 / 4 + 255) / 256, 256, 0, stream>>>(fp, fpb, 512 * 2048 / 4);
  cvt_wfp<<<(128 * 2048 + 255) / 256, 256, 0, stream>>>(W_fp, Wfpt);

  const f16* Wt_pre = Wt;
  const f16* Wt_l1  = Wt + 16384;
  const f16* Wt_r1  = Wt + 32768;
  const f16* Wt_l2  = Wt + 49152;
  const f16* Wt_r2  = Wt + 65536;

  int gGemm = (NN + 127) / 128;  // 782

  // pre_mp: h0 = prelu(x@W_pre + b_pre) -> buf2
  gemm_f16<0><<<gGemm, 256, 0, stream>>>(buf0, nullptr, Wt_pre, nullptr,
                                         b_pre, a_pre, buf2, NN);

  // fingerprint head (overlaps with node pipeline)
  {
    dim3 g(16, 4);
    fp_gemm<<<g, 256, 0, stream>>>(fpb, Wfpt, part);
    fp_fin<<<(512 * 128 + 255) / 256, 256, 0, stream>>>(part, b_fp, a_fp, femb);
  }

  // conv1: agg(h0) -> buf1; h1 = prelu(agg@Wl1 + h0@Wr1 + bl1) -> buf3
  agg_f16<<<NN / 4, 256, 0, stream>>>(buf2, rowptr, colsA, buf1);
  gemm_f16<1><<<gGemm, 256, 0, stream>>>(buf1, buf2, Wt_l1, Wt_r1,
                                         bl1, a1, buf3, NN);

  // conv2: agg(h1) -> buf0; h2 = prelu(agg@Wl2 + h1@Wr2 + bl2) -> buf2 (f16)
  agg_f16<<<NN / 4, 256, 0, stream>>>(buf3, rowptr, colsA, buf0);
  gemm_f16<1><<<gGemm, 256, 0, stream>>>(buf0, buf3, Wt_l2, Wt_r2,
                                         bl2, a2, buf2, NN);

  // pool + final
  pool_mean<<<NG, 512, 0, stream>>>(buf2, batch, pooled);
  final_out<<<NG, 64, 0, stream>>>(pooled, femb, W_post, b_post, (float*)d_out);
}